// Round 8
// baseline (199.164 us; speedup 1.0000x reference)
//
#include <hip/hip_runtime.h>
#include <cstdint>

typedef __attribute__((ext_vector_type(8))) short short8v;  // 8 bf16 (4 VGPR)
typedef __attribute__((ext_vector_type(4))) float f32x4;

#define KCODES 2048
#define CDIM 256
#define HWN 1024
#define MROWS 32768
#define MARGIN 1.0f
#define CAP (1 << 19)
#define KMAX 16

__device__ __forceinline__ unsigned short f2bf(float f) {
  unsigned u = __float_as_uint(f);
  unsigned r = (u + 0x7fffu + ((u >> 16) & 1u)) >> 16;   // RNE
  return (unsigned short)r;
}

// 16-lane idempotent min-reduce steps via DPP (pure VALU, no LDS pipe)
#define FMIN_DPP(v, CTRL) \
  fminf(v, __int_as_float(__builtin_amdgcn_update_dpp( \
      0, __float_as_int(v), CTRL, 0xf, 0xf, true)))

// exact fp32 score for (row,k): IDENTICAL instruction sequence wherever used,
// so slot-path and overflow-path produce bit-identical keys (determinism).
__device__ __forceinline__ unsigned long long score_key(
    const float4 xv, const float* __restrict__ E,
    const float* __restrict__ e2, int k, int lane) {
  const float4 ev = reinterpret_cast<const float4*>(E + (size_t)k * CDIM)[lane];
  float d = fmaf(xv.x, ev.x, fmaf(xv.y, ev.y, fmaf(xv.z, ev.z, xv.w * ev.w)));
  #pragma unroll
  for (int off = 32; off > 0; off >>= 1) d += __shfl_xor(d, off);
  float s = fmaf(-2.f, d, e2[k]);
  unsigned u = __float_as_uint(s);
  u = (u & 0x80000000u) ? ~u : (u | 0x80000000u);   // monotone encode
  return ((unsigned long long)u << 32) | (unsigned)k;
}

// ---------------- prep: transpose + inits (blocks <2048) | e2/Ebf (rest) ----
__global__ __launch_bounds__(256) void prep_kernel(
    const float* __restrict__ X, float* __restrict__ Xrow,
    unsigned short* __restrict__ Xbf,
    unsigned long long* __restrict__ rkey, int* __restrict__ count,
    unsigned* __restrict__ rowcnt,
    const float* __restrict__ E, float* __restrict__ e2,
    unsigned short* __restrict__ Ebf) {
  __shared__ float t[64][65];
  int bid = blockIdx.x;
  if (bid >= 2048) {          // ---- e2 role: one wave per code ----
    int gt = (bid - 2048) * 256 + threadIdx.x;
    int k = gt >> 6, lane = threadIdx.x & 63;
    const float4 v = reinterpret_cast<const float4*>(E + (size_t)k * CDIM)[lane];
    unsigned lo = (unsigned)f2bf(v.x) | ((unsigned)f2bf(v.y) << 16);
    unsigned hi = (unsigned)f2bf(v.z) | ((unsigned)f2bf(v.w) << 16);
    uint2 p; p.x = lo; p.y = hi;
    *reinterpret_cast<uint2*>(Ebf + (size_t)k * CDIM + 4 * lane) = p;
    float s = v.x*v.x + v.y*v.y + v.z*v.z + v.w*v.w;
    #pragma unroll
    for (int off = 32; off > 0; off >>= 1) s += __shfl_down(s, off);
    if (lane == 0) e2[k] = s;
    return;
  }
  // ---- transpose role + inits ----
  int gid = bid * 256 + threadIdx.x;
  if (gid < MROWS) { rkey[gid] = ~0ULL; rowcnt[gid] = 0u; }
  if (gid == 0) *count = 0;
  int b = bid >> 6, rem = bid & 63;
  int c0 = (rem >> 4) * 64, n0 = (rem & 15) * 64;
  int g = threadIdx.x >> 6, lane = threadIdx.x & 63;
  const float* xb = X + ((size_t)b * CDIM) * HWN;
  #pragma unroll
  for (int i = 0; i < 16; ++i) {
    int c = g * 16 + i;
    t[c][lane] = xb[(size_t)(c0 + c) * HWN + n0 + lane];   // coalesced read
  }
  __syncthreads();
  #pragma unroll
  for (int i = 0; i < 16; ++i) {
    int nn = g * 16 + i;
    float v = t[lane][nn];                                 // 2-way (free)
    size_t row = (size_t)b * HWN + n0 + nn;
    Xrow[row * CDIM + c0 + lane] = v;                      // coalesced write
    Xbf [row * CDIM + c0 + lane] = f2bf(v);
  }
}

// ---------------- MFMA approx-distance, single-pass prefix threshold --------
// 128 rows x 1024 codes per block; 16 chunks of 64 codes, double-buffered LDS
// staged via global_load_lds (pre-swizzled source). Per chunk: MFMA -> scores
// in registers -> per-row chunk min via fmin tree + 4 DPP steps -> runmin ->
// insert s <= runmin+MARGIN into the per-row slot table (32K counters: no
// contention). Overflow beyond KMAX slots -> flat list (statistically never).
__global__ __launch_bounds__(256, 2) void cand_kernel(
    const unsigned short* __restrict__ Xbf,
    const unsigned short* __restrict__ Ebf,
    const float* __restrict__ e2,
    unsigned* __restrict__ rowcnt, unsigned short* __restrict__ rowslot,
    unsigned* __restrict__ list, int* __restrict__ count)
{
  __shared__ unsigned short elds[2][16384];   // 2 x 32 KB
  __shared__ float e2l[1024];                 // 4 KB

  const int tid = threadIdx.x;
  const int wave = tid >> 6, lane = tid & 63;
  const int l15 = lane & 15, l4 = lane >> 4;
  const int rowblk = blockIdx.x >> 1;
  const int nhalf = blockIdx.x & 1;
  const int row0 = rowblk * 128 + wave * 32;
  const int code0 = nhalf * 1024;

  // e2 for this code-half -> LDS
  {
    float4 ev = *reinterpret_cast<const float4*>(e2 + code0 + tid * 4);
    *reinterpret_cast<float4*>(&e2l[tid * 4]) = ev;
  }

  // A fragments: 32 rows x 256 ch bf16 resident in registers (64 VGPR)
  short8v af[2][8];
  #pragma unroll
  for (int mt = 0; mt < 2; ++mt)
    #pragma unroll
    for (int kt = 0; kt < 8; ++kt)
      af[mt][kt] = *reinterpret_cast<const short8v*>(
          Xbf + (size_t)(row0 + mt * 16 + l15) * CDIM + kt * 32 + l4 * 8);

  // per-lane pre-swizzled staging source base
  const int r0 = 2 * wave + (lane >> 5);                  // 0..7
  const int soff = r0 * 512 + (((lane & 31) * 16) ^ (r0 << 4));
  const char* srcbase = (const char*)Ebf + (size_t)code0 * 512 + soff;
  char* dst0 = (char*)&elds[0][0] + wave * 1024;
  char* dst1 = (char*)&elds[1][0] + wave * 1024;

  // issue chunk 0 -> buf0
  #pragma unroll
  for (int j = 0; j < 8; ++j)
    __builtin_amdgcn_global_load_lds(
        (const __attribute__((address_space(1))) unsigned int*)(srcbase + j * 4096),
        (__attribute__((address_space(3))) unsigned int*)(dst0 + j * 4096), 16, 0, 0);

  float runmin0[4], runmin1[4];
  #pragma unroll
  for (int r = 0; r < 4; ++r) { runmin0[r] = 3.4e38f; runmin1[r] = 3.4e38f; }

  __syncthreads();   // e2l visible

  #pragma unroll 1
  for (int i = 0; i < 16; ++i) {
    const int cur = i & 1;
    if (i < 15) {   // stage chunk i+1 into the other buffer
      const char* s = srcbase + (size_t)(i + 1) * 32768;
      char* d = cur ? dst0 : dst1;
      #pragma unroll
      for (int j = 0; j < 8; ++j)
        __builtin_amdgcn_global_load_lds(
            (const __attribute__((address_space(1))) unsigned int*)(s + j * 4096),
            (__attribute__((address_space(3))) unsigned int*)(d + j * 4096), 16, 0, 0);
      asm volatile("s_waitcnt vmcnt(8)" ::: "memory");   // this chunk's 8 done
    } else {
      asm volatile("s_waitcnt vmcnt(0)" ::: "memory");
    }
    __builtin_amdgcn_s_barrier();          // all waves: buf[cur] fully written
    asm volatile("" ::: "memory");

    const char* lbase = (const char*)&elds[cur][0];
    const int cc6 = i << 6;
    float s0[4][4], s1[4][4];              // [nsub][r], registers
    #pragma unroll
    for (int nsub = 0; nsub < 4; ++nsub) {
      f32x4 a0 = {0.f, 0.f, 0.f, 0.f}, a1 = {0.f, 0.f, 0.f, 0.f};
      const int rn = nsub * 16 + l15;
      const char* lb = lbase + rn * 512;
      const int sw = (rn & 7) << 4;
      #pragma unroll
      for (int kt = 0; kt < 8; ++kt) {
        short8v bf = *reinterpret_cast<const short8v*>(lb + ((kt * 64 + l4 * 16) ^ sw));
        a0 = __builtin_amdgcn_mfma_f32_16x16x32_bf16(af[0][kt], bf, a0, 0, 0, 0);
        a1 = __builtin_amdgcn_mfma_f32_16x16x32_bf16(af[1][kt], bf, a1, 0, 0, 0);
      }
      const float e2v = e2l[cc6 + (nsub << 4) + l15];
      #pragma unroll
      for (int r = 0; r < 4; ++r) {
        s0[nsub][r] = fmaf(-2.f, a0[r], e2v);
        s1[nsub][r] = fmaf(-2.f, a1[r], e2v);
      }
    }

    // per-row chunk min: fmin tree over nsub (VALU) + 4 DPP steps (16 lanes)
    float thr0[4], thr1[4];
    #pragma unroll
    for (int r = 0; r < 4; ++r) {
      float c0m = fminf(fminf(s0[0][r], s0[1][r]), fminf(s0[2][r], s0[3][r]));
      float c1m = fminf(fminf(s1[0][r], s1[1][r]), fminf(s1[2][r], s1[3][r]));
      c0m = FMIN_DPP(c0m, 0xB1); c0m = FMIN_DPP(c0m, 0x4E);
      c0m = FMIN_DPP(c0m, 0x141); c0m = FMIN_DPP(c0m, 0x140);
      c1m = FMIN_DPP(c1m, 0xB1); c1m = FMIN_DPP(c1m, 0x4E);
      c1m = FMIN_DPP(c1m, 0x141); c1m = FMIN_DPP(c1m, 0x140);
      runmin0[r] = fminf(runmin0[r], c0m);  thr0[r] = runmin0[r] + MARGIN;
      runmin1[r] = fminf(runmin1[r], c1m);  thr1[r] = runmin1[r] + MARGIN;
    }

    // rare inserts -> per-row slot table (contention-free atomics)
    #pragma unroll
    for (int nsub = 0; nsub < 4; ++nsub) {
      const int code = code0 + cc6 + (nsub << 4) + l15;
      #pragma unroll
      for (int r = 0; r < 4; ++r) {
        if (s0[nsub][r] <= thr0[r]) {
          int row = row0 + 4 * l4 + r;
          unsigned pos = atomicAdd(&rowcnt[row], 1u);
          if (pos < KMAX) rowslot[row * KMAX + pos] = (unsigned short)code;
          else { int gp = atomicAdd(count, 1);
                 if (gp < CAP) list[gp] = ((unsigned)row << 11) | (unsigned)code; }
        }
        if (s1[nsub][r] <= thr1[r]) {
          int row = row0 + 16 + 4 * l4 + r;
          unsigned pos = atomicAdd(&rowcnt[row], 1u);
          if (pos < KMAX) rowslot[row * KMAX + pos] = (unsigned short)code;
          else { int gp = atomicAdd(count, 1);
                 if (gp < CAP) list[gp] = ((unsigned)row << 11) | (unsigned)code; }
        }
      }
    }
    __builtin_amdgcn_s_barrier();   // all waves done reading buf[cur]
    asm volatile("" ::: "memory");
  }
}

// ---------------- exact fp32 refine: row-grouped (X read ONCE per row) ------
__global__ __launch_bounds__(256) void refine_kernel(
    const float* __restrict__ Xrow, const float* __restrict__ E,
    const float* __restrict__ e2,
    const unsigned* __restrict__ rowcnt, const unsigned short* __restrict__ rowslot,
    const unsigned* __restrict__ list, const int* __restrict__ count,
    unsigned long long* __restrict__ rkey)
{
  const int lane = threadIdx.x & 63;
  const int wid = (blockIdx.x * 256 + threadIdx.x) >> 6;   // 0..4095
  #pragma unroll 1
  for (int rr = 0; rr < 8; ++rr) {
    const int row = wid * 8 + rr;
    const float4 xv = reinterpret_cast<const float4*>(Xrow + (size_t)row * CDIM)[lane];
    int cnt = (int)rowcnt[row]; if (cnt > KMAX) cnt = KMAX;
    unsigned long long best = ~0ULL;
    for (int i = 0; i < cnt; ++i) {
      int k = rowslot[row * KMAX + i];
      unsigned long long key = score_key(xv, E, e2, k, lane);
      if (key < best) best = key;
    }
    if (lane == 0) atomicMin(&rkey[row], best);
  }
  // overflow tail (statistically empty): flat-list entries, same score path
  int cnt = *count; if (cnt > CAP) cnt = CAP;
  #pragma unroll 1
  for (int i = wid; i < cnt; i += 4096) {
    unsigned p = list[i];
    int row = p >> 11, k = p & 2047;
    const float4 xv = reinterpret_cast<const float4*>(Xrow + (size_t)row * CDIM)[lane];
    unsigned long long key = score_key(xv, E, e2, k, lane);
    if (lane == 0) atomicMin(&rkey[row], key);
  }
}

// ---------------- gather codebook rows + MSE partials (reads rkey) ----------
__global__ __launch_bounds__(256) void out_kernel(
    const float* __restrict__ X, const float* __restrict__ E,
    const unsigned long long* __restrict__ rkey, float* __restrict__ out,
    float* __restrict__ partial)
{
  __shared__ float warpsum[4];
  size_t t = (size_t)blockIdx.x * 256 + threadIdx.x;
  size_t base = t * 8;
  float lsum = 0.f;
  #pragma unroll
  for (int g = 0; g < 2; ++g) {
    size_t e0 = base + (size_t)g * 4;
    int b = (int)(e0 >> 18);
    int c = (int)((e0 >> 10) & 255);
    int n = (int)(e0 & 1023);
    const unsigned long long* kp = rkey + b * HWN + n;
    int i0 = (int)(kp[0] & 2047ULL), i1 = (int)(kp[1] & 2047ULL);
    int i2 = (int)(kp[2] & 2047ULL), i3 = (int)(kp[3] & 2047ULL);
    float4 q;
    q.x = E[(size_t)i0 * CDIM + c];
    q.y = E[(size_t)i1 * CDIM + c];
    q.z = E[(size_t)i2 * CDIM + c];
    q.w = E[(size_t)i3 * CDIM + c];
    const float4 xv = *reinterpret_cast<const float4*>(X + e0);
    *reinterpret_cast<float4*>(out + e0) = q;
    float dx = xv.x - q.x, dy = xv.y - q.y, dz = xv.z - q.z, dw = xv.w - q.w;
    lsum += dx*dx + dy*dy + dz*dz + dw*dw;
  }
  #pragma unroll
  for (int off = 32; off > 0; off >>= 1) lsum += __shfl_down(lsum, off);
  int lane = threadIdx.x & 63, wv = threadIdx.x >> 6;
  if (lane == 0) warpsum[wv] = lsum;
  __syncthreads();
  if (threadIdx.x == 0)
    partial[blockIdx.x] = warpsum[0] + warpsum[1] + warpsum[2] + warpsum[3];
}

// ---------------- deterministic final loss reduce ---------------------------
__global__ __launch_bounds__(256) void loss_kernel(const float* __restrict__ partial,
                                                   float* __restrict__ out_loss) {
  __shared__ double sd[256];
  double s = 0.0;
  for (int i = threadIdx.x; i < 4096; i += 256) s += (double)partial[i];
  sd[threadIdx.x] = s;
  __syncthreads();
  if (threadIdx.x == 0) {
    double tot = 0.0;
    for (int i = 0; i < 256; ++i) tot += sd[i];
    out_loss[0] = (float)(tot / 8388608.0);
  }
}

extern "C" void kernel_launch(void* const* d_in, const int* in_sizes, int n_in,
                              void* d_out, int out_size, void* d_ws, size_t ws_size,
                              hipStream_t stream) {
  const float* X = (const float*)d_in[0];   // [32,256,32,32] fp32
  const float* E = (const float*)d_in[1];   // [2048,256] fp32
  float* out = (float*)d_out;               // 8388608 quantized + 1 loss
  char* ws = (char*)d_ws;

  float*              e2      = (float*)(ws + 0);                 // 8 KB
  unsigned short*     Ebf     = (unsigned short*)(ws + 8192);     // 1 MB
  unsigned short*     Xbf     = (unsigned short*)(ws + 1056768);  // 16 MB
  unsigned long long* rkey    = (unsigned long long*)(ws + 17833984); // 256 KB
  int*                count   = (int*)(ws + 18096128);            // 256 B
  unsigned*           rowcnt  = (unsigned*)(ws + 18096384);       // 128 KB
  unsigned*           list    = (unsigned*)(ws + 18227456);       // 2 MB
  unsigned short*     rowslot = (unsigned short*)(ws + 20324608); // 1 MB
  float*              partial = (float*)(ws + 21373184);          // 16 KB
  float* Xrow = out;   // fp32 row-major X stashed in d_out; overwritten by out_kernel

  prep_kernel  <<<2560, 256, 0, stream>>>(X, Xrow, Xbf, rkey, count, rowcnt, E, e2, Ebf);
  cand_kernel  <<<512,  256, 0, stream>>>(Xbf, Ebf, e2, rowcnt, rowslot, list, count);
  refine_kernel<<<1024, 256, 0, stream>>>(Xrow, E, e2, rowcnt, rowslot, list, count, rkey);
  out_kernel   <<<4096, 256, 0, stream>>>(X, E, rkey, out, partial);
  loss_kernel  <<<1,    256, 0, stream>>>(partial, out + 8388608);
}

// Round 9
// 169.257 us; speedup vs baseline: 1.1767x; 1.1767x over previous
//
#include <hip/hip_runtime.h>
#include <cstdint>

typedef __attribute__((ext_vector_type(8))) short short8v;  // 8 bf16 (4 VGPR)
typedef __attribute__((ext_vector_type(4))) float f32x4;

#define KCODES 2048
#define CDIM 256
#define HWN 1024
#define MROWS 32768
#define MARGIN 1.0f
#define CAP (1 << 19)
#define KMAX 16
#define LCAP 2048

__device__ __forceinline__ unsigned short f2bf(float f) {
  unsigned u = __float_as_uint(f);
  unsigned r = (u + 0x7fffu + ((u >> 16) & 1u)) >> 16;   // RNE
  return (unsigned short)r;
}

// 16-lane idempotent min-reduce steps via DPP (pure VALU, no LDS pipe)
#define FMIN_DPP(v, CTRL) \
  fminf(v, __int_as_float(__builtin_amdgcn_update_dpp( \
      0, __float_as_int(v), CTRL, 0xf, 0xf, true)))

// exact fp32 score for (row,k): IDENTICAL instruction sequence wherever used,
// so slot-path and overflow-path produce bit-identical keys (determinism).
__device__ __forceinline__ unsigned long long score_key(
    const float4 xv, const float* __restrict__ E,
    const float* __restrict__ e2, int k, int lane) {
  const float4 ev = reinterpret_cast<const float4*>(E + (size_t)k * CDIM)[lane];
  float d = fmaf(xv.x, ev.x, fmaf(xv.y, ev.y, fmaf(xv.z, ev.z, xv.w * ev.w)));
  #pragma unroll
  for (int off = 32; off > 0; off >>= 1) d += __shfl_xor(d, off);
  float s = fmaf(-2.f, d, e2[k]);
  unsigned u = __float_as_uint(s);
  u = (u & 0x80000000u) ? ~u : (u | 0x80000000u);   // monotone encode
  return ((unsigned long long)u << 32) | (unsigned)k;
}

// ---------------- prep: transpose + inits (blocks <2048) | e2/Ebf (rest) ----
__global__ __launch_bounds__(256) void prep_kernel(
    const float* __restrict__ X, float* __restrict__ Xrow,
    unsigned short* __restrict__ Xbf,
    unsigned long long* __restrict__ rkey, int* __restrict__ count,
    unsigned* __restrict__ rowcnt,
    const float* __restrict__ E, float* __restrict__ e2,
    unsigned short* __restrict__ Ebf) {
  __shared__ float t[64][65];
  int bid = blockIdx.x;
  if (bid >= 2048) {          // ---- e2 role: one wave per code ----
    int gt = (bid - 2048) * 256 + threadIdx.x;
    int k = gt >> 6, lane = threadIdx.x & 63;
    const float4 v = reinterpret_cast<const float4*>(E + (size_t)k * CDIM)[lane];
    unsigned lo = (unsigned)f2bf(v.x) | ((unsigned)f2bf(v.y) << 16);
    unsigned hi = (unsigned)f2bf(v.z) | ((unsigned)f2bf(v.w) << 16);
    uint2 p; p.x = lo; p.y = hi;
    *reinterpret_cast<uint2*>(Ebf + (size_t)k * CDIM + 4 * lane) = p;
    float s = v.x*v.x + v.y*v.y + v.z*v.z + v.w*v.w;
    #pragma unroll
    for (int off = 32; off > 0; off >>= 1) s += __shfl_down(s, off);
    if (lane == 0) e2[k] = s;
    return;
  }
  // ---- transpose role + inits ----
  int gid = bid * 256 + threadIdx.x;
  if (gid < MROWS) { rkey[gid] = ~0ULL; rowcnt[gid] = 0u; }
  if (gid == 0) *count = 0;
  int b = bid >> 6, rem = bid & 63;
  int c0 = (rem >> 4) * 64, n0 = (rem & 15) * 64;
  int g = threadIdx.x >> 6, lane = threadIdx.x & 63;
  const float* xb = X + ((size_t)b * CDIM) * HWN;
  #pragma unroll
  for (int i = 0; i < 16; ++i) {
    int c = g * 16 + i;
    t[c][lane] = xb[(size_t)(c0 + c) * HWN + n0 + lane];   // coalesced read
  }
  __syncthreads();
  #pragma unroll
  for (int i = 0; i < 16; ++i) {
    int nn = g * 16 + i;
    float v = t[lane][nn];                                 // 2-way (free)
    size_t row = (size_t)b * HWN + n0 + nn;
    Xrow[row * CDIM + c0 + lane] = v;                      // coalesced write
    Xbf [row * CDIM + c0 + lane] = f2bf(v);
  }
}

// ---------------- MFMA approx-distance, single-pass prefix threshold --------
// 128 rows x 1024 codes per block; 16 chunks of 64 codes, double-buffered LDS
// staged via global_load_lds (pre-swizzled source). Per chunk: MFMA -> scores
// in registers -> per-row chunk min via fmin tree + 4 DPP steps -> runmin ->
// insert s <= runmin+MARGIN into the LDS cbuf (LDS atomic: no vmcnt drain on
// the critical path -- r8's global-atomic inserts serialized the pipeline).
// At kernel end the block publishes cbuf into the per-row slot table.
__global__ __launch_bounds__(256, 2) void cand_kernel(
    const unsigned short* __restrict__ Xbf,
    const unsigned short* __restrict__ Ebf,
    const float* __restrict__ e2,
    unsigned* __restrict__ rowcnt, unsigned short* __restrict__ rowslot,
    unsigned* __restrict__ list, int* __restrict__ count)
{
  __shared__ unsigned short elds[2][16384];   // 2 x 32 KB
  __shared__ float e2l[1024];                 // 4 KB
  __shared__ unsigned cbuf[LCAP];             // 8 KB
  __shared__ int lcount;

  const int tid = threadIdx.x;
  const int wave = tid >> 6, lane = tid & 63;
  const int l15 = lane & 15, l4 = lane >> 4;
  const int rowblk = blockIdx.x >> 1;
  const int nhalf = blockIdx.x & 1;
  const int row0 = rowblk * 128 + wave * 32;
  const int code0 = nhalf * 1024;

  if (tid == 0) lcount = 0;

  // e2 for this code-half -> LDS
  {
    float4 ev = *reinterpret_cast<const float4*>(e2 + code0 + tid * 4);
    *reinterpret_cast<float4*>(&e2l[tid * 4]) = ev;
  }

  // A fragments: 32 rows x 256 ch bf16 resident in registers (64 VGPR)
  short8v af[2][8];
  #pragma unroll
  for (int mt = 0; mt < 2; ++mt)
    #pragma unroll
    for (int kt = 0; kt < 8; ++kt)
      af[mt][kt] = *reinterpret_cast<const short8v*>(
          Xbf + (size_t)(row0 + mt * 16 + l15) * CDIM + kt * 32 + l4 * 8);

  // per-lane pre-swizzled staging source base
  const int r0 = 2 * wave + (lane >> 5);                  // 0..7
  const int soff = r0 * 512 + (((lane & 31) * 16) ^ (r0 << 4));
  const char* srcbase = (const char*)Ebf + (size_t)code0 * 512 + soff;
  char* dst0 = (char*)&elds[0][0] + wave * 1024;
  char* dst1 = (char*)&elds[1][0] + wave * 1024;

  // issue chunk 0 -> buf0
  #pragma unroll
  for (int j = 0; j < 8; ++j)
    __builtin_amdgcn_global_load_lds(
        (const __attribute__((address_space(1))) unsigned int*)(srcbase + j * 4096),
        (__attribute__((address_space(3))) unsigned int*)(dst0 + j * 4096), 16, 0, 0);

  float runmin0[4], runmin1[4];
  #pragma unroll
  for (int r = 0; r < 4; ++r) { runmin0[r] = 3.4e38f; runmin1[r] = 3.4e38f; }

  __syncthreads();   // e2l + lcount visible

  #pragma unroll 1
  for (int i = 0; i < 16; ++i) {
    const int cur = i & 1;
    if (i < 15) {   // stage chunk i+1 into the other buffer
      const char* s = srcbase + (size_t)(i + 1) * 32768;
      char* d = cur ? dst0 : dst1;
      #pragma unroll
      for (int j = 0; j < 8; ++j)
        __builtin_amdgcn_global_load_lds(
            (const __attribute__((address_space(1))) unsigned int*)(s + j * 4096),
            (__attribute__((address_space(3))) unsigned int*)(d + j * 4096), 16, 0, 0);
      asm volatile("s_waitcnt vmcnt(8)" ::: "memory");   // this chunk's 8 done
    } else {
      asm volatile("s_waitcnt vmcnt(0)" ::: "memory");
    }
    __builtin_amdgcn_s_barrier();          // all waves: buf[cur] fully written
    asm volatile("" ::: "memory");

    const char* lbase = (const char*)&elds[cur][0];
    const int cc6 = i << 6;
    float s0[4][4], s1[4][4];              // [nsub][r], registers
    #pragma unroll
    for (int nsub = 0; nsub < 4; ++nsub) {
      f32x4 a0 = {0.f, 0.f, 0.f, 0.f}, a1 = {0.f, 0.f, 0.f, 0.f};
      const int rn = nsub * 16 + l15;
      const char* lb = lbase + rn * 512;
      const int sw = (rn & 7) << 4;
      #pragma unroll
      for (int kt = 0; kt < 8; ++kt) {
        short8v bf = *reinterpret_cast<const short8v*>(lb + ((kt * 64 + l4 * 16) ^ sw));
        a0 = __builtin_amdgcn_mfma_f32_16x16x32_bf16(af[0][kt], bf, a0, 0, 0, 0);
        a1 = __builtin_amdgcn_mfma_f32_16x16x32_bf16(af[1][kt], bf, a1, 0, 0, 0);
      }
      const float e2v = e2l[cc6 + (nsub << 4) + l15];
      #pragma unroll
      for (int r = 0; r < 4; ++r) {
        s0[nsub][r] = fmaf(-2.f, a0[r], e2v);
        s1[nsub][r] = fmaf(-2.f, a1[r], e2v);
      }
    }

    // per-row chunk min: fmin tree over nsub (VALU) + 4 DPP steps (16 lanes)
    float thr0[4], thr1[4];
    #pragma unroll
    for (int r = 0; r < 4; ++r) {
      float c0m = fminf(fminf(s0[0][r], s0[1][r]), fminf(s0[2][r], s0[3][r]));
      float c1m = fminf(fminf(s1[0][r], s1[1][r]), fminf(s1[2][r], s1[3][r]));
      c0m = FMIN_DPP(c0m, 0xB1); c0m = FMIN_DPP(c0m, 0x4E);
      c0m = FMIN_DPP(c0m, 0x141); c0m = FMIN_DPP(c0m, 0x140);
      c1m = FMIN_DPP(c1m, 0xB1); c1m = FMIN_DPP(c1m, 0x4E);
      c1m = FMIN_DPP(c1m, 0x141); c1m = FMIN_DPP(c1m, 0x140);
      runmin0[r] = fminf(runmin0[r], c0m);  thr0[r] = runmin0[r] + MARGIN;
      runmin1[r] = fminf(runmin1[r], c1m);  thr1[r] = runmin1[r] + MARGIN;
    }

    // rare inserts -> LDS cbuf (LDS atomic only; vmcnt untouched)
    #pragma unroll
    for (int nsub = 0; nsub < 4; ++nsub) {
      const int code = code0 + cc6 + (nsub << 4) + l15;
      #pragma unroll
      for (int r = 0; r < 4; ++r) {
        if (s0[nsub][r] <= thr0[r]) {
          unsigned entry = ((unsigned)(row0 + 4 * l4 + r) << 11) | (unsigned)code;
          int pos = atomicAdd(&lcount, 1);
          if (pos < LCAP) cbuf[pos] = entry;
          else {   // statistically never (mean ~293 per block)
            unsigned sp = atomicAdd(&rowcnt[entry >> 11], 1u);
            if (sp < KMAX) rowslot[(entry >> 11) * KMAX + sp] = (unsigned short)code;
            else { int gp = atomicAdd(count, 1); if (gp < CAP) list[gp] = entry; }
          }
        }
        if (s1[nsub][r] <= thr1[r]) {
          unsigned entry = ((unsigned)(row0 + 16 + 4 * l4 + r) << 11) | (unsigned)code;
          int pos = atomicAdd(&lcount, 1);
          if (pos < LCAP) cbuf[pos] = entry;
          else {
            unsigned sp = atomicAdd(&rowcnt[entry >> 11], 1u);
            if (sp < KMAX) rowslot[(entry >> 11) * KMAX + sp] = (unsigned short)code;
            else { int gp = atomicAdd(count, 1); if (gp < CAP) list[gp] = entry; }
          }
        }
      }
    }
    __builtin_amdgcn_s_barrier();   // all waves done reading buf[cur]
    asm volatile("" ::: "memory");
  }

  // ---- publish cbuf -> per-row slot table (off the critical path) ----
  __syncthreads();
  int lc = lcount; if (lc > LCAP) lc = LCAP;
  for (int i = tid; i < lc; i += 256) {
    unsigned entry = cbuf[i];
    unsigned row = entry >> 11;
    unsigned short code = (unsigned short)(entry & 2047u);
    unsigned sp = atomicAdd(&rowcnt[row], 1u);
    if (sp < KMAX) rowslot[row * KMAX + sp] = code;
    else { int gp = atomicAdd(count, 1); if (gp < CAP) list[gp] = entry; }
  }
}

// ---------------- exact fp32 refine: row-grouped (X read ONCE per row) ------
__global__ __launch_bounds__(256) void refine_kernel(
    const float* __restrict__ Xrow, const float* __restrict__ E,
    const float* __restrict__ e2,
    const unsigned* __restrict__ rowcnt, const unsigned short* __restrict__ rowslot,
    const unsigned* __restrict__ list, const int* __restrict__ count,
    unsigned long long* __restrict__ rkey)
{
  const int lane = threadIdx.x & 63;
  const int wid = (blockIdx.x * 256 + threadIdx.x) >> 6;   // 0..4095
  #pragma unroll 1
  for (int rr = 0; rr < 8; ++rr) {
    const int row = wid * 8 + rr;
    const float4 xv = reinterpret_cast<const float4*>(Xrow + (size_t)row * CDIM)[lane];
    int cnt = (int)rowcnt[row]; if (cnt > KMAX) cnt = KMAX;
    unsigned long long best = ~0ULL;
    for (int i = 0; i < cnt; ++i) {
      int k = rowslot[row * KMAX + i];
      unsigned long long key = score_key(xv, E, e2, k, lane);
      if (key < best) best = key;
    }
    if (lane == 0) atomicMin(&rkey[row], best);
  }
  // overflow tail (statistically empty): flat-list entries, same score path
  int cnt = *count; if (cnt > CAP) cnt = CAP;
  #pragma unroll 1
  for (int i = wid; i < cnt; i += 4096) {
    unsigned p = list[i];
    int row = p >> 11, k = p & 2047;
    const float4 xv = reinterpret_cast<const float4*>(Xrow + (size_t)row * CDIM)[lane];
    unsigned long long key = score_key(xv, E, e2, k, lane);
    if (lane == 0) atomicMin(&rkey[row], key);
  }
}

// ---------------- gather codebook rows + MSE partials (reads rkey) ----------
__global__ __launch_bounds__(256) void out_kernel(
    const float* __restrict__ X, const float* __restrict__ E,
    const unsigned long long* __restrict__ rkey, float* __restrict__ out,
    float* __restrict__ partial)
{
  __shared__ float warpsum[4];
  size_t t = (size_t)blockIdx.x * 256 + threadIdx.x;
  size_t base = t * 8;
  float lsum = 0.f;
  #pragma unroll
  for (int g = 0; g < 2; ++g) {
    size_t e0 = base + (size_t)g * 4;
    int b = (int)(e0 >> 18);
    int c = (int)((e0 >> 10) & 255);
    int n = (int)(e0 & 1023);
    const unsigned long long* kp = rkey + b * HWN + n;
    int i0 = (int)(kp[0] & 2047ULL), i1 = (int)(kp[1] & 2047ULL);
    int i2 = (int)(kp[2] & 2047ULL), i3 = (int)(kp[3] & 2047ULL);
    float4 q;
    q.x = E[(size_t)i0 * CDIM + c];
    q.y = E[(size_t)i1 * CDIM + c];
    q.z = E[(size_t)i2 * CDIM + c];
    q.w = E[(size_t)i3 * CDIM + c];
    const float4 xv = *reinterpret_cast<const float4*>(X + e0);
    *reinterpret_cast<float4*>(out + e0) = q;
    float dx = xv.x - q.x, dy = xv.y - q.y, dz = xv.z - q.z, dw = xv.w - q.w;
    lsum += dx*dx + dy*dy + dz*dz + dw*dw;
  }
  #pragma unroll
  for (int off = 32; off > 0; off >>= 1) lsum += __shfl_down(lsum, off);
  int lane = threadIdx.x & 63, wv = threadIdx.x >> 6;
  if (lane == 0) warpsum[wv] = lsum;
  __syncthreads();
  if (threadIdx.x == 0)
    partial[blockIdx.x] = warpsum[0] + warpsum[1] + warpsum[2] + warpsum[3];
}

// ---------------- deterministic final loss reduce ---------------------------
__global__ __launch_bounds__(256) void loss_kernel(const float* __restrict__ partial,
                                                   float* __restrict__ out_loss) {
  __shared__ double sd[256];
  double s = 0.0;
  for (int i = threadIdx.x; i < 4096; i += 256) s += (double)partial[i];
  sd[threadIdx.x] = s;
  __syncthreads();
  if (threadIdx.x == 0) {
    double tot = 0.0;
    for (int i = 0; i < 256; ++i) tot += sd[i];
    out_loss[0] = (float)(tot / 8388608.0);
  }
}

extern "C" void kernel_launch(void* const* d_in, const int* in_sizes, int n_in,
                              void* d_out, int out_size, void* d_ws, size_t ws_size,
                              hipStream_t stream) {
  const float* X = (const float*)d_in[0];   // [32,256,32,32] fp32
  const float* E = (const float*)d_in[1];   // [2048,256] fp32
  float* out = (float*)d_out;               // 8388608 quantized + 1 loss
  char* ws = (char*)d_ws;

  float*              e2      = (float*)(ws + 0);                 // 8 KB
  unsigned short*     Ebf     = (unsigned short*)(ws + 8192);     // 1 MB
  unsigned short*     Xbf     = (unsigned short*)(ws + 1056768);  // 16 MB
  unsigned long long* rkey    = (unsigned long long*)(ws + 17833984); // 256 KB
  int*                count   = (int*)(ws + 18096128);            // 256 B
  unsigned*           rowcnt  = (unsigned*)(ws + 18096384);       // 128 KB
  unsigned*           list    = (unsigned*)(ws + 18227456);       // 2 MB
  unsigned short*     rowslot = (unsigned short*)(ws + 20324608); // 1 MB
  float*              partial = (float*)(ws + 21373184);          // 16 KB
  float* Xrow = out;   // fp32 row-major X stashed in d_out; overwritten by out_kernel

  prep_kernel  <<<2560, 256, 0, stream>>>(X, Xrow, Xbf, rkey, count, rowcnt, E, e2, Ebf);
  cand_kernel  <<<512,  256, 0, stream>>>(Xbf, Ebf, e2, rowcnt, rowslot, list, count);
  refine_kernel<<<1024, 256, 0, stream>>>(Xrow, E, e2, rowcnt, rowslot, list, count, rkey);
  out_kernel   <<<4096, 256, 0, stream>>>(X, E, rkey, out, partial);
  loss_kernel  <<<1,    256, 0, stream>>>(partial, out + 8388608);
}